// Round 5
// baseline (81.952 us; speedup 1.0000x reference)
//
#include <hip/hip_runtime.h>

// PSANet 'distribute':
// out[n, h*W + w, i, j] = x[n, (i-h+63)*127 + (j-w+63), h, w], N=2, H=W=64.
//
// Block = 4 (h,i) pairs on one wrapped diagonal u=(i-h)&63 (same di except at
// the wrap) -> per dj-plane the block reads 4 ADJACENT 256B rows (~1 KB DRAM
// page window) issued back-to-back by one wave. Band-predicated float4 loads
// (no over-fetch). LDS scatter lane map (wl,djo) keeps banks at 2-way (free).
// Store: dense float4 per pair, 64x256B chunks @16KiB stride (unchanged).
// XCD swizzle: each XCD gets contiguous diagonals.

#define PSA_H 64
#define PSA_W 64
#define PSA_HM 127
#define PSA_WM 127
#define PSA_HW (PSA_H * PSA_W)      // 4096
#define PSA_CHW (PSA_HM * PSA_WM)   // 16129
#define NPAIR 4

__global__ __launch_bounds__(512) void psa_distribute_kernel(
    const float* __restrict__ in, float* __restrict__ out) {
    __shared__ float lds[NPAIR * PSA_HW];  // 64 KiB: lds[p][w][j]

    const int b   = blockIdx.x;
    // 2048 blocks; round-robin dispatch -> each XCD owns a contiguous s-range
    const int xcd = b & 7;
    const int s   = (xcd << 8) + (b >> 3);
    const int n   = s >> 10;
    const int u   = (s >> 4) & 63;       // wrapped diagonal: i = (h+u)&63
    const int h0  = (s & 15) << 2;       // h-chunk of 4

    size_t in_base[NPAIR];
    size_t out_base[NPAIR];
#pragma unroll
    for (int p = 0; p < NPAIR; ++p) {
        const int h  = h0 + p;
        const int i  = (h + u) & 63;
        const int di = i - h + (PSA_H - 1);   // u+63 or u-1
        in_base[p]  = ((size_t)n * PSA_CHW + (size_t)di * PSA_WM) * PSA_HW
                      + (size_t)h * PSA_W;
        out_base[p] = ((size_t)n * PSA_HW + (size_t)h * PSA_W) * PSA_HW
                      + (size_t)i * PSA_W;
    }

    const int t     = threadIdx.x;
    const int wl    = t & 15;            // float4 column
    const int djo   = (t >> 4) & 3;      // dj sub-offset (lane dim -> LDS banks ok)
    const int wv    = t >> 6;            // wave 0..7
    const int wbase = wl << 2;

#pragma unroll
    for (int it = 0; it < 4; ++it) {
        const int dj = it * 32 + wv * 4 + djo;        // 0..127
        // valid w range for this dj: [63-dj, 126-dj] clipped to [0,63]
        const bool row_ok = (dj < PSA_WM) &&
                            (wbase + 3 >= PSA_W - 1 - dj) &&
                            (wbase <= 2 * (PSA_W - 1) - dj);
        if (row_ok) {
            const int jb = dj + wbase - (PSA_W - 1);
#pragma unroll
            for (int p = 0; p < NPAIR; ++p) {
                const float4 v = *(const float4*)(
                    in + in_base[p] + (size_t)dj * PSA_HW + wbase);
#pragma unroll
                for (int e = 0; e < 4; ++e) {
                    const int j = jb + e;
                    if ((unsigned)j < (unsigned)PSA_W) {
                        lds[p * PSA_HW + (wbase + e) * PSA_W + j] =
                            ((const float*)&v)[e];
                    }
                }
            }
        }
    }
    __syncthreads();

    const float4* lds4 = (const float4*)lds;
#pragma unroll
    for (int it = 0; it < 8; ++it) {
        const int idx = it * 512 + t;    // 0..4095 = p*1024 + w*16 + j4
        const int p   = idx >> 10;
        const int rem = idx & 1023;
        const int w   = rem >> 4;
        const int j4  = rem & 15;
        float4* dst = (float4*)(out + out_base[p]);
        dst[w * (PSA_HW / 4) + j4] = lds4[idx];
    }
}

extern "C" void kernel_launch(void* const* d_in, const int* in_sizes, int n_in,
                              void* d_out, int out_size, void* d_ws, size_t ws_size,
                              hipStream_t stream) {
    const float* x = (const float*)d_in[0];
    float* out = (float*)d_out;
    const int nblocks = 2 * PSA_H * PSA_H / NPAIR;  // 2048
    psa_distribute_kernel<<<nblocks, 512, 0, stream>>>(x, out);
}

// Round 6
// 70.962 us; speedup vs baseline: 1.1549x; 1.1549x over previous
//
#include <hip/hip_runtime.h>

// PSANet 'distribute':
// out[n, h*W + w, i, j] = x[n, (i-h+63)*127 + (j-w+63), h, w], N=2, H=W=64.
//
// R6: R5's read-grouping WITHOUT the occupancy loss.
// Block = 2 (h,i) pairs on one wrapped diagonal u=(i-h)&63: per dj the two
// loads hit ADJACENT 256B rows (512B contiguous window), issued back-to-back.
// 512 threads, 32 KiB LDS -> 4 blocks/CU (thread-limited) x 8 waves
// = 32 waves/CU: full occupancy, same as R4.
// Loads band-predicated float4 (line-optimal fetch, ~199MB).
// LDS scatter banks: (djo+4wl+e+c)%32 -> exact 2-way = free.
// Store: dense float4, 1KB/instruction (unchanged).
// XCD swizzle: round-robin dispatch -> each XCD owns a contiguous s-range.

#define PSA_H 64
#define PSA_W 64
#define PSA_HM 127
#define PSA_WM 127
#define PSA_HW (PSA_H * PSA_W)      // 4096
#define PSA_CHW (PSA_HM * PSA_WM)   // 16129
#define NPAIR 2

__global__ __launch_bounds__(512) void psa_distribute_kernel(
    const float* __restrict__ in, float* __restrict__ out) {
    __shared__ float lds[NPAIR * PSA_HW];  // 32 KiB: lds[p][w][j]

    const int b   = blockIdx.x;            // grid = 4096
    const int xcd = b & 7;
    const int s   = (xcd << 9) + (b >> 3); // contiguous 512-range per XCD
    const int n   = s >> 11;
    const int r   = s & 2047;
    const int u   = (r >> 5) & 63;         // wrapped diagonal: i = (h+u)&63
    const int h0  = (r & 31) << 1;         // h-chunk of 2

    size_t in_base[NPAIR];
    size_t out_base[NPAIR];
#pragma unroll
    for (int p = 0; p < NPAIR; ++p) {
        const int h  = h0 + p;
        const int i  = (h + u) & 63;
        const int di = i - h + (PSA_H - 1);
        in_base[p]  = ((size_t)n * PSA_CHW + (size_t)di * PSA_WM) * PSA_HW
                      + (size_t)h * PSA_W;
        out_base[p] = ((size_t)n * PSA_HW + (size_t)h * PSA_W) * PSA_HW
                      + (size_t)i * PSA_W;
    }

    const int t     = threadIdx.x;
    const int wl    = t & 15;            // float4 column
    const int djo   = (t >> 4) & 3;      // dj sub-offset
    const int wv    = t >> 6;            // wave 0..7
    const int wbase = wl << 2;

#pragma unroll
    for (int it = 0; it < 4; ++it) {
        const int dj = it * 32 + wv * 4 + djo;        // 0..127 (127 masked)
        // valid w range for this dj: [63-dj, 126-dj] clipped to [0,63]
        const bool row_ok = (dj < PSA_WM) &&
                            (wbase + 3 >= PSA_W - 1 - dj) &&
                            (wbase <= 2 * (PSA_W - 1) - dj);
        if (row_ok) {
            const int jb = dj + wbase - (PSA_W - 1);
#pragma unroll
            for (int p = 0; p < NPAIR; ++p) {
                const float4 v = *(const float4*)(
                    in + in_base[p] + (size_t)dj * PSA_HW + wbase);
#pragma unroll
                for (int e = 0; e < 4; ++e) {
                    const int j = jb + e;
                    if ((unsigned)j < (unsigned)PSA_W) {
                        lds[p * PSA_HW + (wbase + e) * PSA_W + j] =
                            ((const float*)&v)[e];
                    }
                }
            }
        }
    }
    __syncthreads();

    const float4* lds4 = (const float4*)lds;
#pragma unroll
    for (int it = 0; it < 4; ++it) {
        const int idx = it * 512 + t;    // 0..2047 = p*1024 + w*16 + j4
        const int p   = idx >> 10;
        const int rem = idx & 1023;
        const int w   = rem >> 4;
        const int j4  = rem & 15;
        float4* dst = (float4*)(out + out_base[p]);
        dst[w * (PSA_HW / 4) + j4] = lds4[idx];
    }
}

extern "C" void kernel_launch(void* const* d_in, const int* in_sizes, int n_in,
                              void* d_out, int out_size, void* d_ws, size_t ws_size,
                              hipStream_t stream) {
    const float* x = (const float*)d_in[0];
    float* out = (float*)d_out;
    const int nblocks = 2 * PSA_H * PSA_H / NPAIR;  // 4096
    psa_distribute_kernel<<<nblocks, 512, 0, stream>>>(x, out);
}